// Round 2
// baseline (5942.638 us; speedup 1.0000x reference)
//
#include <hip/hip_runtime.h>

#define N_IN 128
#define NHEADS 8
#define DHEAD 16

// ---------------------------------------------------------------------------
// Projection: Q/K/V = h @ W{q,k,v} + b{q,k,v}
// 32 nodes per block, 256 threads, 4x4 register tile per thread.
// h tile staged in LDS (stride 129 to dodge bank conflicts); each W staged
// in two 32KB k-chunks (keeps LDS at ~48.5KB -> 3 blocks/CU).
// ---------------------------------------------------------------------------
__global__ __launch_bounds__(256) void gat_proj_50766513439004(
    const float* __restrict__ hin,
    const float* __restrict__ Wq, const float* __restrict__ Wk, const float* __restrict__ Wv,
    const float* __restrict__ bq, const float* __restrict__ bk, const float* __restrict__ bv,
    float* __restrict__ Q, float* __restrict__ K, float* __restrict__ V, int N)
{
    __shared__ float hs[32][129];
    __shared__ float ws[64 * 128];

    const int t   = threadIdx.x;
    const int nb0 = blockIdx.x * 32;

    // stage 32 h-rows
    for (int i = t; i < 32 * 128; i += 256) {
        int r = i >> 7, c = i & 127;
        int node = nb0 + r;
        hs[r][c] = (node < N) ? hin[(size_t)node * 128 + c] : 0.0f;
    }

    const int cg   = t & 31;   // column group (0..31)
    const int ng   = t >> 5;   // node group   (0..7)
    const int col0 = cg * 4;
    const int row0 = ng * 4;

    const float* Wm[3] = {Wq, Wk, Wv};
    const float* bm[3] = {bq, bk, bv};
    float*       Om[3] = {Q, K, V};

    for (int m = 0; m < 3; ++m) {
        float acc[4][4];
        #pragma unroll
        for (int j = 0; j < 4; ++j) {
            float b = bm[m][col0 + j];
            acc[0][j] = b; acc[1][j] = b; acc[2][j] = b; acc[3][j] = b;
        }

        for (int kc = 0; kc < 128; kc += 64) {
            __syncthreads();   // protects hs staging (1st iter) & ws reuse
            const float4* Wg = (const float4*)(Wm[m] + (size_t)kc * 128);
            float4*       Wl = (float4*)ws;
            #pragma unroll
            for (int i = 0; i < 8; ++i)
                Wl[t + i * 256] = Wg[t + i * 256];
            __syncthreads();

            #pragma unroll 8
            for (int k = 0; k < 64; ++k) {
                float a0 = hs[row0 + 0][kc + k];
                float a1 = hs[row0 + 1][kc + k];
                float a2 = hs[row0 + 2][kc + k];
                float a3 = hs[row0 + 3][kc + k];
                float4 w = *(const float4*)&ws[k * 128 + col0];
                acc[0][0] += a0 * w.x; acc[0][1] += a0 * w.y; acc[0][2] += a0 * w.z; acc[0][3] += a0 * w.w;
                acc[1][0] += a1 * w.x; acc[1][1] += a1 * w.y; acc[1][2] += a1 * w.z; acc[1][3] += a1 * w.w;
                acc[2][0] += a2 * w.x; acc[2][1] += a2 * w.y; acc[2][2] += a2 * w.z; acc[2][3] += a2 * w.w;
                acc[3][0] += a3 * w.x; acc[3][1] += a3 * w.y; acc[3][2] += a3 * w.z; acc[3][3] += a3 * w.w;
            }
        }

        float* O = Om[m];
        #pragma unroll
        for (int i = 0; i < 4; ++i) {
            int node = nb0 + row0 + i;
            if (node < N) {
                float4 o = make_float4(acc[i][0], acc[i][1], acc[i][2], acc[i][3]);
                *(float4*)&O[(size_t)node * 128 + col0] = o;
            }
        }
    }
}

// ---------------------------------------------------------------------------
// Edge phase: thread = (edge, head). score = exp(clip(K[src].Q[dst]/4,-5,5));
// atomically scatter score*V[src] into out[dst] and score into z[dst].
// ---------------------------------------------------------------------------
__global__ __launch_bounds__(256) void gat_edge_50766513439004(
    const float* __restrict__ Q, const float* __restrict__ K, const float* __restrict__ V,
    const int* __restrict__ src, const int* __restrict__ dst,
    float* __restrict__ out, float* __restrict__ z, int E)
{
    long long tid = (long long)blockIdx.x * blockDim.x + threadIdx.x;
    long long e   = tid >> 3;
    if (e >= E) return;
    int hh = (int)(tid & 7);

    int s = src[e], d = dst[e];

    const float4* kp = (const float4*)&K[(size_t)s * 128 + hh * 16];
    const float4* qp = (const float4*)&Q[(size_t)d * 128 + hh * 16];

    float dot = 0.0f;
    #pragma unroll
    for (int i = 0; i < 4; ++i) {
        float4 kv = kp[i], qv = qp[i];
        dot += kv.x * qv.x + kv.y * qv.y + kv.z * qv.z + kv.w * qv.w;
    }
    float sc = __expf(fminf(fmaxf(dot * 0.25f, -5.0f), 5.0f));

    atomicAdd(&z[(size_t)d * 8 + hh], sc);

    const float4* vp = (const float4*)&V[(size_t)s * 128 + hh * 16];
    float* op = &out[(size_t)d * 128 + hh * 16];
    #pragma unroll
    for (int i = 0; i < 4; ++i) {
        float4 vv = vp[i];
        atomicAdd(op + 4 * i + 0, vv.x * sc);
        atomicAdd(op + 4 * i + 1, vv.y * sc);
        atomicAdd(op + 4 * i + 2, vv.z * sc);
        atomicAdd(op + 4 * i + 3, vv.w * sc);
    }
}

// ---------------------------------------------------------------------------
// Normalize: out[n,h,:] /= z[n,h]. One float4 per thread; tid>>2 == n*8+h.
// ---------------------------------------------------------------------------
__global__ __launch_bounds__(256) void gat_norm_50766513439004(
    float* __restrict__ out, const float* __restrict__ z, int N)
{
    int tid = blockIdx.x * blockDim.x + threadIdx.x;
    if (tid >= N * 32) return;
    float zi = z[tid >> 2];
    float4* o4 = (float4*)out;
    float4 v = o4[tid];
    v.x /= zi; v.y /= zi; v.z /= zi; v.w /= zi;
    o4[tid] = v;
}

extern "C" void kernel_launch(void* const* d_in, const int* in_sizes, int n_in,
                              void* d_out, int out_size, void* d_ws, size_t ws_size,
                              hipStream_t stream) {
    const float* hin = (const float*)d_in[0];
    const int*   src = (const int*)d_in[1];
    const int*   dst = (const int*)d_in[2];
    const float* Wq  = (const float*)d_in[3];
    const float* Wk  = (const float*)d_in[4];
    const float* Wv  = (const float*)d_in[5];
    const float* bq  = (const float*)d_in[6];
    const float* bk  = (const float*)d_in[7];
    const float* bv  = (const float*)d_in[8];

    const int N = in_sizes[0] / 128;
    const int E = in_sizes[1];

    float* out = (float*)d_out;
    float* Q   = (float*)d_ws;
    float* K   = Q + (size_t)N * 128;
    float* V   = K + (size_t)N * 128;
    float* z   = V + (size_t)N * 128;

    // zero accumulators (harness poisons d_out/d_ws with 0xAA; never restored)
    hipMemsetAsync(out, 0, (size_t)N * 128 * sizeof(float), stream);
    hipMemsetAsync(z,   0, (size_t)N * 8   * sizeof(float), stream);

    gat_proj_50766513439004<<<(N + 31) / 32, 256, 0, stream>>>(
        hin, Wq, Wk, Wv, bq, bk, bv, Q, K, V, N);

    long long ethreads = (long long)E * 8;
    gat_edge_50766513439004<<<(int)((ethreads + 255) / 256), 256, 0, stream>>>(
        Q, K, V, src, dst, out, z, E);

    gat_norm_50766513439004<<<(N * 32 + 255) / 256, 256, 0, stream>>>(out, z, N);
}

// Round 3
// 387.571 us; speedup vs baseline: 15.3330x; 15.3330x over previous
//
#include <hip/hip_runtime.h>

#define N_IN 128
#define NHEADS 8
#define DHEAD 16

// ---------------------------------------------------------------------------
// Projection: Q/K/V = h @ W{q,k,v} + b{q,k,v}
// 32 nodes per block, 256 threads, 4x4 register tile per thread.
// ---------------------------------------------------------------------------
__global__ __launch_bounds__(256) void gat_proj_50766513439004(
    const float* __restrict__ hin,
    const float* __restrict__ Wq, const float* __restrict__ Wk, const float* __restrict__ Wv,
    const float* __restrict__ bq, const float* __restrict__ bk, const float* __restrict__ bv,
    float* __restrict__ Q, float* __restrict__ K, float* __restrict__ V, int N)
{
    __shared__ float hs[32][129];
    __shared__ float ws[64 * 128];

    const int t   = threadIdx.x;
    const int nb0 = blockIdx.x * 32;

    for (int i = t; i < 32 * 128; i += 256) {
        int r = i >> 7, c = i & 127;
        int node = nb0 + r;
        hs[r][c] = (node < N) ? hin[(size_t)node * 128 + c] : 0.0f;
    }

    const int cg   = t & 31;
    const int ng   = t >> 5;
    const int col0 = cg * 4;
    const int row0 = ng * 4;

    const float* Wm[3] = {Wq, Wk, Wv};
    const float* bm[3] = {bq, bk, bv};
    float*       Om[3] = {Q, K, V};

    for (int m = 0; m < 3; ++m) {
        float acc[4][4];
        #pragma unroll
        for (int j = 0; j < 4; ++j) {
            float b = bm[m][col0 + j];
            acc[0][j] = b; acc[1][j] = b; acc[2][j] = b; acc[3][j] = b;
        }

        for (int kc = 0; kc < 128; kc += 64) {
            __syncthreads();
            const float4* Wg = (const float4*)(Wm[m] + (size_t)kc * 128);
            float4*       Wl = (float4*)ws;
            #pragma unroll
            for (int i = 0; i < 8; ++i)
                Wl[t + i * 256] = Wg[t + i * 256];
            __syncthreads();

            #pragma unroll 8
            for (int k = 0; k < 64; ++k) {
                float a0 = hs[row0 + 0][kc + k];
                float a1 = hs[row0 + 1][kc + k];
                float a2 = hs[row0 + 2][kc + k];
                float a3 = hs[row0 + 3][kc + k];
                float4 w = *(const float4*)&ws[k * 128 + col0];
                acc[0][0] += a0 * w.x; acc[0][1] += a0 * w.y; acc[0][2] += a0 * w.z; acc[0][3] += a0 * w.w;
                acc[1][0] += a1 * w.x; acc[1][1] += a1 * w.y; acc[1][2] += a1 * w.z; acc[1][3] += a1 * w.w;
                acc[2][0] += a2 * w.x; acc[2][1] += a2 * w.y; acc[2][2] += a2 * w.z; acc[2][3] += a2 * w.w;
                acc[3][0] += a3 * w.x; acc[3][1] += a3 * w.y; acc[3][2] += a3 * w.z; acc[3][3] += a3 * w.w;
            }
        }

        float* O = Om[m];
        #pragma unroll
        for (int i = 0; i < 4; ++i) {
            int node = nb0 + row0 + i;
            if (node < N) {
                float4 o = make_float4(acc[i][0], acc[i][1], acc[i][2], acc[i][3]);
                *(float4*)&O[(size_t)node * 128 + col0] = o;
            }
        }
    }
}

// ---------------------------------------------------------------------------
// CSR build step 1: per-dst degree count (int atomics only)
// ---------------------------------------------------------------------------
__global__ __launch_bounds__(256) void gat_count_50766513439004(
    const int* __restrict__ dst, int* __restrict__ deg, int E)
{
    int e = blockIdx.x * blockDim.x + threadIdx.x;
    if (e < E) atomicAdd(&deg[dst[e]], 1);
}

// ---------------------------------------------------------------------------
// CSR build step 2: single-block exclusive scan of deg -> row_start[0..N]
// 1024 threads; each thread handles a contiguous chunk; Hillis-Steele on
// per-thread totals in LDS.
// ---------------------------------------------------------------------------
__global__ __launch_bounds__(1024) void gat_scan_50766513439004(
    const int* __restrict__ deg, int* __restrict__ row_start, int N)
{
    __shared__ int part[1024];
    const int t = threadIdx.x;
    const int chunk = (N + 1023) / 1024;
    const int lo = t * chunk;
    const int hi = min(lo + chunk, N);

    int s = 0;
    for (int i = lo; i < hi; ++i) s += deg[i];
    part[t] = s;
    __syncthreads();

    for (int off = 1; off < 1024; off <<= 1) {
        int v = (t >= off) ? part[t - off] : 0;
        __syncthreads();
        if (t >= off) part[t] += v;
        __syncthreads();
    }

    int run = (t > 0) ? part[t - 1] : 0;   // exclusive prefix
    for (int i = lo; i < hi; ++i) { row_start[i] = run; run += deg[i]; }
    if (t == 1023) row_start[N] = part[1023];
}

// ---------------------------------------------------------------------------
// CSR build step 3: scatter src indices into dst-grouped order
// ---------------------------------------------------------------------------
__global__ __launch_bounds__(256) void gat_scatter_50766513439004(
    const int* __restrict__ src, const int* __restrict__ dst,
    int* __restrict__ cursor, int* __restrict__ esrc, int E)
{
    int e = blockIdx.x * blockDim.x + threadIdx.x;
    if (e < E) {
        int pos = atomicAdd(&cursor[dst[e]], 1);
        esrc[pos] = src[e];
    }
}

// ---------------------------------------------------------------------------
// Gather: one wave per dst node. lane = h*8 + p, owns output dims
// col = h*16 + 2p (+1). Per edge: coalesced float2 reads of K[src],V[src];
// per-head dot via 3x shfl_xor within the 8-lane head group; register
// accumulation; fused normalization; each output written exactly once.
// ---------------------------------------------------------------------------
__global__ __launch_bounds__(256) void gat_gather_50766513439004(
    const float* __restrict__ Q, const float* __restrict__ K, const float* __restrict__ V,
    const int* __restrict__ row_start, const int* __restrict__ esrc,
    float* __restrict__ out, int N)
{
    int wid  = (blockIdx.x * blockDim.x + threadIdx.x) >> 6;   // node id
    if (wid >= N) return;
    int lane = threadIdx.x & 63;
    int col  = (lane >> 3) * 16 + (lane & 7) * 2;              // h*16 + 2p

    float2 q = *(const float2*)&Q[(size_t)wid * 128 + col];

    int lo = row_start[wid], hi = row_start[wid + 1];

    float acc0 = 0.0f, acc1 = 0.0f, zacc = 0.0f;

    int s_next = (lo < hi) ? esrc[lo] : 0;
    for (int i = lo; i < hi; ++i) {
        int s = s_next;
        if (i + 1 < hi) s_next = esrc[i + 1];

        float2 kv = *(const float2*)&K[(size_t)s * 128 + col];
        float2 vv = *(const float2*)&V[(size_t)s * 128 + col];

        float part = kv.x * q.x + kv.y * q.y;
        part += __shfl_xor(part, 1, 64);
        part += __shfl_xor(part, 2, 64);
        part += __shfl_xor(part, 4, 64);

        float sc = __expf(fminf(fmaxf(part * 0.25f, -5.0f), 5.0f));

        acc0 += vv.x * sc;
        acc1 += vv.y * sc;
        zacc += sc;
    }

    float inv = 1.0f / zacc;
    float2 o = make_float2(acc0 * inv, acc1 * inv);
    *(float2*)&out[(size_t)wid * 128 + col] = o;
}

extern "C" void kernel_launch(void* const* d_in, const int* in_sizes, int n_in,
                              void* d_out, int out_size, void* d_ws, size_t ws_size,
                              hipStream_t stream) {
    const float* hin = (const float*)d_in[0];
    const int*   src = (const int*)d_in[1];
    const int*   dst = (const int*)d_in[2];
    const float* Wq  = (const float*)d_in[3];
    const float* Wk  = (const float*)d_in[4];
    const float* Wv  = (const float*)d_in[5];
    const float* bq  = (const float*)d_in[6];
    const float* bk  = (const float*)d_in[7];
    const float* bv  = (const float*)d_in[8];

    const int N = in_sizes[0] / 128;
    const int E = in_sizes[1];

    float* out = (float*)d_out;
    float* Q   = (float*)d_ws;
    float* K   = Q + (size_t)N * 128;
    float* V   = K + (size_t)N * 128;
    int* ibase     = (int*)(V + (size_t)N * 128);
    int* deg       = ibase;                 // N
    int* row_start = deg + N;               // N+1
    int* cursor    = row_start + N + 1;     // N
    int* esrc      = cursor + N;            // E

    hipMemsetAsync(deg, 0, (size_t)N * sizeof(int), stream);

    gat_proj_50766513439004<<<(N + 31) / 32, 256, 0, stream>>>(
        hin, Wq, Wk, Wv, bq, bk, bv, Q, K, V, N);

    gat_count_50766513439004<<<(E + 255) / 256, 256, 0, stream>>>(dst, deg, E);

    gat_scan_50766513439004<<<1, 1024, 0, stream>>>(deg, row_start, N);

    hipMemcpyAsync(cursor, row_start, (size_t)N * sizeof(int),
                   hipMemcpyDeviceToDevice, stream);

    gat_scatter_50766513439004<<<(E + 255) / 256, 256, 0, stream>>>(
        src, dst, cursor, esrc, E);

    int gather_blocks = (N * 64 + 255) / 256;   // one wave per node, 4 waves/block
    gat_gather_50766513439004<<<gather_blocks, 256, 0, stream>>>(
        Q, K, V, row_start, esrc, out, N);
}

// Round 4
// 257.819 us; speedup vs baseline: 23.0496x; 1.5033x over previous
//
#include <hip/hip_runtime.h>
#include <hip/hip_bf16.h>

#define NHEADS 8
#define DHEAD 16

typedef __attribute__((ext_vector_type(8))) short short8;
typedef __attribute__((ext_vector_type(4))) float f32x4;

__device__ __forceinline__ short f2bf(float f) {
    __hip_bfloat16 b = __float2bfloat16(f);
    return *reinterpret_cast<short*>(&b);
}
__device__ __forceinline__ float bflo(unsigned u) { return __uint_as_float(u << 16); }
__device__ __forceinline__ float bfhi(unsigned u) { return __uint_as_float(u & 0xffff0000u); }

// ---------------------------------------------------------------------------
// Prep: (a) per-dst degree count (int atomics); (b) convert W{q,k,v} fp32 ->
// bf16 in MFMA-B-fragment order:
//   wswz[(((m*8+nt)*4+kb)*64+lane)*8 + j] = W_m[(kb*32+(lane>>4)*8+j)*128 + nt*16+(lane&15)]
// ---------------------------------------------------------------------------
__global__ __launch_bounds__(256) void gat_prep_50766513439004(
    const float* __restrict__ Wq, const float* __restrict__ Wk, const float* __restrict__ Wv,
    const int* __restrict__ dst, int* __restrict__ deg, short* __restrict__ wswz, int E)
{
    int tid = blockIdx.x * 256 + threadIdx.x;
    if (tid < E) atomicAdd(&deg[dst[tid]], 1);
    if (tid < 3 * 8 * 4 * 64) {
        int lane = tid & 63;
        int kb   = (tid >> 6) & 3;
        int nt   = (tid >> 8) & 7;
        int m    = tid >> 11;
        const float* W = (m == 0) ? Wq : (m == 1) ? Wk : Wv;
        int n  = nt * 16 + (lane & 15);
        int k0 = kb * 32 + (lane >> 4) * 8;
        short8 v;
        #pragma unroll
        for (int j = 0; j < 8; ++j) v[j] = f2bf(W[(size_t)(k0 + j) * 128 + n]);
        *(short8*)&wswz[(size_t)tid * 8] = v;
    }
}

// ---------------------------------------------------------------------------
// Projection via MFMA bf16: Q (fp32) and KV interleaved bf16 [node][K0..127|V0..127].
// Block = 4 waves; wave w owns nodes m0 = blk*64 + w*16 .. +15.
// A frag: lane holds h[m0+(lane&15)][kb*32+(lane>>4)*8 + j], j=0..7 (cvt to bf16).
// D frag: col = lane&15, row = (lane>>4)*4 + reg  [m89-verified layout].
// ---------------------------------------------------------------------------
__global__ __launch_bounds__(256) void gat_proj_50766513439004(
    const float* __restrict__ hin, const short* __restrict__ wswz,
    const float* __restrict__ bq, const float* __restrict__ bk, const float* __restrict__ bv,
    float* __restrict__ Q, short* __restrict__ KV, int N)
{
    const int wave = threadIdx.x >> 6;
    const int lane = threadIdx.x & 63;
    const int m0   = blockIdx.x * 64 + wave * 16;

    const int arow = m0 + (lane & 15);
    const int arc  = (arow < N) ? arow : (N - 1);
    const int koff = (lane >> 4) * 8;

    short8 afrag[4];
    #pragma unroll
    for (int kb = 0; kb < 4; ++kb) {
        const float* p = &hin[(size_t)arc * 128 + kb * 32 + koff];
        float4 x = *(const float4*)p;
        float4 y = *(const float4*)(p + 4);
        short8 a;
        a[0] = f2bf(x.x); a[1] = f2bf(x.y); a[2] = f2bf(x.z); a[3] = f2bf(x.w);
        a[4] = f2bf(y.x); a[5] = f2bf(y.y); a[6] = f2bf(y.z); a[7] = f2bf(y.w);
        afrag[kb] = a;
    }

    const float* bias[3] = {bq, bk, bv};
    const int n_lo = lane & 15;
    const int rbase = m0 + (lane >> 4) * 4;

    #pragma unroll
    for (int m = 0; m < 3; ++m) {
        #pragma unroll
        for (int nt = 0; nt < 8; ++nt) {
            f32x4 acc = {0.f, 0.f, 0.f, 0.f};
            #pragma unroll
            for (int kb = 0; kb < 4; ++kb) {
                short8 bfrag = *(const short8*)&wswz[((((m * 8 + nt) * 4 + kb) * 64 + lane)) * 8];
                acc = __builtin_amdgcn_mfma_f32_16x16x32_bf16(afrag[kb], bfrag, acc, 0, 0, 0);
            }
            const int n = nt * 16 + n_lo;
            const float bval = bias[m][n];
            #pragma unroll
            for (int r = 0; r < 4; ++r) {
                int node = rbase + r;
                if (node < N) {
                    float val = acc[r] + bval;
                    if (m == 0) {
                        Q[(size_t)node * 128 + n] = val;
                    } else {
                        KV[(size_t)node * 256 + (m == 2 ? 128 : 0) + n] = f2bf(val);
                    }
                }
            }
        }
    }
}

// ---------------------------------------------------------------------------
// CSR scan: single block, exclusive prefix over deg -> row_start[0..N]
// ---------------------------------------------------------------------------
__global__ __launch_bounds__(1024) void gat_scan_50766513439004(
    const int* __restrict__ deg, int* __restrict__ row_start, int N)
{
    __shared__ int part[1024];
    const int t = threadIdx.x;
    const int chunk = (N + 1023) / 1024;
    const int lo = t * chunk;
    const int hi = min(lo + chunk, N);

    int s = 0;
    for (int i = lo; i < hi; ++i) s += deg[i];
    part[t] = s;
    __syncthreads();

    for (int off = 1; off < 1024; off <<= 1) {
        int v = (t >= off) ? part[t - off] : 0;
        __syncthreads();
        if (t >= off) part[t] += v;
        __syncthreads();
    }

    int run = (t > 0) ? part[t - 1] : 0;
    for (int i = lo; i < hi; ++i) { row_start[i] = run; run += deg[i]; }
    if (t == 1023) row_start[N] = part[1023];
}

// ---------------------------------------------------------------------------
// CSR scatter: src indices into dst-grouped order
// ---------------------------------------------------------------------------
__global__ __launch_bounds__(256) void gat_scatter_50766513439004(
    const int* __restrict__ src, const int* __restrict__ dst,
    int* __restrict__ cursor, int* __restrict__ esrc, int E)
{
    int e = blockIdx.x * blockDim.x + threadIdx.x;
    if (e < E) {
        int pos = atomicAdd(&cursor[dst[e]], 1);
        esrc[pos] = src[e];
    }
}

// ---------------------------------------------------------------------------
// Gather: one wave per dst node, 2 edges per iteration.
// lane = sub*32 + l5; sub in {0,1} picks edge i+sub. l5: head = l5>>2, p = l5&3,
// owns dims col = head*16 + p*4 .. +3. K/V read as 8B bf16x4 from interleaved KV.
// Per-head dot reduced over 4 lanes (2 shfl_xor); halves combined at the end.
// ---------------------------------------------------------------------------
__global__ __launch_bounds__(256) void gat_gather_50766513439004(
    const float* __restrict__ Q, const short* __restrict__ KV,
    const int* __restrict__ row_start, const int* __restrict__ esrc,
    float* __restrict__ out, int N)
{
    int wid = (blockIdx.x * blockDim.x + threadIdx.x) >> 6;
    if (wid >= N) return;
    const int lane = threadIdx.x & 63;
    const int sub  = lane >> 5;
    const int l5   = lane & 31;
    const int col  = (l5 >> 2) * 16 + (l5 & 3) * 4;

    const float4 q = *(const float4*)&Q[(size_t)wid * 128 + col];
    const int lo = row_start[wid], hi = row_start[wid + 1];

    float a0 = 0.f, a1 = 0.f, a2 = 0.f, a3 = 0.f, z = 0.f;

    for (int i = lo; i < hi; i += 2) {
        const int e = i + sub;
        const bool valid = (e < hi);
        const int s = valid ? esrc[e] : esrc[i];

        const size_t base = (size_t)s * 256 + col;
        const uint2 kk = *(const uint2*)&KV[base];
        const uint2 vv = *(const uint2*)&KV[base + 128];

        float dot = bflo(kk.x) * q.x + bfhi(kk.x) * q.y
                  + bflo(kk.y) * q.z + bfhi(kk.y) * q.w;
        dot += __shfl_xor(dot, 1, 64);
        dot += __shfl_xor(dot, 2, 64);

        float sc = valid ? __expf(fminf(fmaxf(dot * 0.25f, -5.0f), 5.0f)) : 0.f;

        a0 += bflo(vv.x) * sc;
        a1 += bfhi(vv.x) * sc;
        a2 += bflo(vv.y) * sc;
        a3 += bfhi(vv.y) * sc;
        z  += sc;
    }

    z  += __shfl_xor(z, 32, 64);
    a0 += __shfl_xor(a0, 32, 64);
    a1 += __shfl_xor(a1, 32, 64);
    a2 += __shfl_xor(a2, 32, 64);
    a3 += __shfl_xor(a3, 32, 64);

    if (sub == 0) {
        float inv = 1.0f / z;
        float4 o = make_float4(a0 * inv, a1 * inv, a2 * inv, a3 * inv);
        *(float4*)&out[(size_t)wid * 128 + col] = o;
    }
}

extern "C" void kernel_launch(void* const* d_in, const int* in_sizes, int n_in,
                              void* d_out, int out_size, void* d_ws, size_t ws_size,
                              hipStream_t stream) {
    const float* hin = (const float*)d_in[0];
    const int*   src = (const int*)d_in[1];
    const int*   dst = (const int*)d_in[2];
    const float* Wq  = (const float*)d_in[3];
    const float* Wk  = (const float*)d_in[4];
    const float* Wv  = (const float*)d_in[5];
    const float* bq  = (const float*)d_in[6];
    const float* bk  = (const float*)d_in[7];
    const float* bv  = (const float*)d_in[8];

    const int N = in_sizes[0] / 128;
    const int E = in_sizes[1];

    float* out = (float*)d_out;

    // workspace layout (all chunks 16B-aligned)
    float* Q      = (float*)d_ws;                       // N*128 fp32
    short* KV     = (short*)(Q + (size_t)N * 128);      // N*256 bf16 (K|V interleaved)
    short* wswz   = KV + (size_t)N * 256;               // 3*8*4*64*8 = 49152 bf16
    int*   deg    = (int*)(wswz + 49152);               // N
    int*   cursor = deg + N;                            // N
    int*   esrc   = cursor + N;                         // E
    int*   row_start = esrc + E;                        // N+1

    hipMemsetAsync(deg, 0, (size_t)N * sizeof(int), stream);

    gat_prep_50766513439004<<<(E + 255) / 256, 256, 0, stream>>>(
        Wq, Wk, Wv, dst, deg, wswz, E);

    gat_proj_50766513439004<<<(N + 63) / 64, 256, 0, stream>>>(
        hin, wswz, bq, bk, bv, Q, KV, N);

    gat_scan_50766513439004<<<1, 1024, 0, stream>>>(deg, row_start, N);

    hipMemcpyAsync(cursor, row_start, (size_t)N * sizeof(int),
                   hipMemcpyDeviceToDevice, stream);

    gat_scatter_50766513439004<<<(E + 255) / 256, 256, 0, stream>>>(
        src, dst, cursor, esrc, E);

    int gather_blocks = (N * 64 + 255) / 256;
    gat_gather_50766513439004<<<gather_blocks, 256, 0, stream>>>(
        Q, KV, row_start, esrc, out, N);
}

// Round 5
// 196.998 us; speedup vs baseline: 30.1660x; 1.3087x over previous
//
#include <hip/hip_runtime.h>
#include <hip/hip_bf16.h>

#define NHEADS 8
#define DHEAD 16

typedef __attribute__((ext_vector_type(8))) short short8;
typedef __attribute__((ext_vector_type(4))) float f32x4;

__device__ __forceinline__ short f2bf(float f) {
    __hip_bfloat16 b = __float2bfloat16(f);
    return *reinterpret_cast<short*>(&b);
}
__device__ __forceinline__ float bflo(unsigned u) { return __uint_as_float(u << 16); }
__device__ __forceinline__ float bfhi(unsigned u) { return __uint_as_float(u & 0xffff0000u); }

// ---------------------------------------------------------------------------
// Prep: (a) per-dst degree count (int atomics); (b) convert W{q,k,v} fp32 ->
// bf16 in MFMA-B-fragment order:
//   wswz[(((m*8+nt)*4+kb)*64+lane)*8 + j] = W_m[(kb*32+(lane>>4)*8+j)*128 + nt*16+(lane&15)]
// ---------------------------------------------------------------------------
__global__ __launch_bounds__(256) void gat_prep_50766513439004(
    const float* __restrict__ Wq, const float* __restrict__ Wk, const float* __restrict__ Wv,
    const int* __restrict__ dst, int* __restrict__ deg, short* __restrict__ wswz, int E)
{
    int tid = blockIdx.x * 256 + threadIdx.x;
    if (tid < E) atomicAdd(&deg[dst[tid]], 1);
    if (tid < 3 * 8 * 4 * 64) {
        int lane = tid & 63;
        int kb   = (tid >> 6) & 3;
        int nt   = (tid >> 8) & 7;
        int m    = tid >> 11;
        const float* W = (m == 0) ? Wq : (m == 1) ? Wk : Wv;
        int n  = nt * 16 + (lane & 15);
        int k0 = kb * 32 + (lane >> 4) * 8;
        short8 v;
        #pragma unroll
        for (int j = 0; j < 8; ++j) v[j] = f2bf(W[(size_t)(k0 + j) * 128 + n]);
        *(short8*)&wswz[(size_t)tid * 8] = v;
    }
}

// ---------------------------------------------------------------------------
// Projection via MFMA bf16.
// Q stays fp32 [node][128]. K,V are bf16, group-interleaved:
//   KV[node*256 + (n>>2)*8 + (n&3)]     = K[node][n]
//   KV[node*256 + (n>>2)*8 + 4 + (n&3)] = V[node][n]
// so gather lane l5 reads one uint4 at node*256 + l5*8 (512B row coalesced).
// D frag: col = lane&15, row = (lane>>4)*4 + reg  [m89-verified layout].
// ---------------------------------------------------------------------------
__global__ __launch_bounds__(256) void gat_proj_50766513439004(
    const float* __restrict__ hin, const short* __restrict__ wswz,
    const float* __restrict__ bq, const float* __restrict__ bk, const float* __restrict__ bv,
    float* __restrict__ Q, short* __restrict__ KV, int N)
{
    const int wave = threadIdx.x >> 6;
    const int lane = threadIdx.x & 63;
    const int m0   = blockIdx.x * 64 + wave * 16;

    const int arow = m0 + (lane & 15);
    const int arc  = (arow < N) ? arow : (N - 1);
    const int koff = (lane >> 4) * 8;

    short8 afrag[4];
    #pragma unroll
    for (int kb = 0; kb < 4; ++kb) {
        const float* p = &hin[(size_t)arc * 128 + kb * 32 + koff];
        float4 x = *(const float4*)p;
        float4 y = *(const float4*)(p + 4);
        short8 a;
        a[0] = f2bf(x.x); a[1] = f2bf(x.y); a[2] = f2bf(x.z); a[3] = f2bf(x.w);
        a[4] = f2bf(y.x); a[5] = f2bf(y.y); a[6] = f2bf(y.z); a[7] = f2bf(y.w);
        afrag[kb] = a;
    }

    const float* bias[3] = {bq, bk, bv};
    const int n_lo = lane & 15;
    const int rbase = m0 + (lane >> 4) * 4;

    #pragma unroll
    for (int m = 0; m < 3; ++m) {
        #pragma unroll
        for (int nt = 0; nt < 8; ++nt) {
            f32x4 acc = {0.f, 0.f, 0.f, 0.f};
            #pragma unroll
            for (int kb = 0; kb < 4; ++kb) {
                short8 bfrag = *(const short8*)&wswz[((((m * 8 + nt) * 4 + kb) * 64 + lane)) * 8];
                acc = __builtin_amdgcn_mfma_f32_16x16x32_bf16(afrag[kb], bfrag, acc, 0, 0, 0);
            }
            const int n = nt * 16 + n_lo;
            const float bval = bias[m][n];
            #pragma unroll
            for (int r = 0; r < 4; ++r) {
                int node = rbase + r;
                if (node < N) {
                    float val = acc[r] + bval;
                    if (m == 0) {
                        Q[(size_t)node * 128 + n] = val;
                    } else {
                        KV[(size_t)node * 256 + (n >> 2) * 8 + (m == 2 ? 4 : 0) + (n & 3)] = f2bf(val);
                    }
                }
            }
        }
    }
}

// ---------------------------------------------------------------------------
// Hierarchical scan, phase 1: per-block (256-elem chunk) sums -> bsum[b]
// ---------------------------------------------------------------------------
__global__ __launch_bounds__(256) void gat_scan_blocks_50766513439004(
    const int* __restrict__ deg, int* __restrict__ bsum, int N)
{
    __shared__ int red[256];
    const int t = threadIdx.x;
    const int i = blockIdx.x * 256 + t;
    red[t] = (i < N) ? deg[i] : 0;
    __syncthreads();
    for (int off = 128; off > 0; off >>= 1) {
        if (t < off) red[t] += red[t + off];
        __syncthreads();
    }
    if (t == 0) bsum[blockIdx.x] = red[0];
}

// ---------------------------------------------------------------------------
// Phase 2: one block, exclusive scan of bsum[0..NB) -> boff (NB <= 256)
// ---------------------------------------------------------------------------
__global__ __launch_bounds__(256) void gat_scan_top_50766513439004(
    const int* __restrict__ bsum, int* __restrict__ boff, int NB)
{
    __shared__ int part[256];
    const int t = threadIdx.x;
    const int v = (t < NB) ? bsum[t] : 0;
    part[t] = v;
    __syncthreads();
    for (int off = 1; off < 256; off <<= 1) {
        int add = (t >= off) ? part[t - off] : 0;
        __syncthreads();
        if (t >= off) part[t] += add;
        __syncthreads();
    }
    if (t < NB) boff[t] = part[t] - v;   // exclusive
}

// ---------------------------------------------------------------------------
// Phase 3: down-sweep. Block-local exclusive scan + boff -> row_start, cursor.
// ---------------------------------------------------------------------------
__global__ __launch_bounds__(256) void gat_scan_down_50766513439004(
    const int* __restrict__ deg, const int* __restrict__ boff,
    int* __restrict__ row_start, int* __restrict__ cursor, int N)
{
    __shared__ int part[256];
    const int t = threadIdx.x;
    const int i = blockIdx.x * 256 + t;
    const int v = (i < N) ? deg[i] : 0;
    part[t] = v;
    __syncthreads();
    for (int off = 1; off < 256; off <<= 1) {
        int add = (t >= off) ? part[t - off] : 0;
        __syncthreads();
        if (t >= off) part[t] += add;
        __syncthreads();
    }
    const int r = boff[blockIdx.x] + part[t] - v;   // exclusive prefix
    if (i < N) { row_start[i] = r; cursor[i] = r; }
    if (i == N - 1) row_start[N] = r + v;
}

// ---------------------------------------------------------------------------
// CSR scatter: src indices into dst-grouped order
// ---------------------------------------------------------------------------
__global__ __launch_bounds__(256) void gat_scatter_50766513439004(
    const int* __restrict__ src, const int* __restrict__ dst,
    int* __restrict__ cursor, int* __restrict__ esrc, int E)
{
    int e = blockIdx.x * blockDim.x + threadIdx.x;
    if (e < E) {
        int pos = atomicAdd(&cursor[dst[e]], 1);
        esrc[pos] = src[e];
    }
}

// ---------------------------------------------------------------------------
// Gather: one wave per dst node, 2 edges per iteration.
// lane = sub*32 + l5; edge = i+sub. l5 owns output dims col = 4*l5..+3
// (head = l5>>2). One uint4 load gives K dims (x,y) and V dims (z,w).
// Per-head dot reduced over 4 lanes (2 shfl_xor); halves combined at end.
// ---------------------------------------------------------------------------
__global__ __launch_bounds__(256) void gat_gather_50766513439004(
    const float* __restrict__ Q, const short* __restrict__ KV,
    const int* __restrict__ row_start, const int* __restrict__ esrc,
    float* __restrict__ out, int N)
{
    int wid = (blockIdx.x * blockDim.x + threadIdx.x) >> 6;
    if (wid >= N) return;
    const int lane = threadIdx.x & 63;
    const int sub  = lane >> 5;
    const int l5   = lane & 31;
    const int col  = l5 * 4;

    const float4 q = *(const float4*)&Q[(size_t)wid * 128 + col];
    const int lo = row_start[wid], hi = row_start[wid + 1];

    float a0 = 0.f, a1 = 0.f, a2 = 0.f, a3 = 0.f, z = 0.f;

    for (int i = lo; i < hi; i += 2) {
        const int e = i + sub;
        const bool valid = (e < hi);
        const int s = valid ? esrc[e] : esrc[i];

        const uint4 kv4 = *(const uint4*)&KV[(size_t)s * 256 + l5 * 8];

        float dot = bflo(kv4.x) * q.x + bfhi(kv4.x) * q.y
                  + bflo(kv4.y) * q.z + bfhi(kv4.y) * q.w;
        dot += __shfl_xor(dot, 1, 64);
        dot += __shfl_xor(dot, 2, 64);

        float sc = valid ? __expf(fminf(fmaxf(dot * 0.25f, -5.0f), 5.0f)) : 0.f;

        a0 += bflo(kv4.z) * sc;
        a1 += bfhi(kv4.z) * sc;
        a2 += bflo(kv4.w) * sc;
        a3 += bfhi(kv4.w) * sc;
        z  += sc;
    }

    z  += __shfl_xor(z, 32, 64);
    a0 += __shfl_xor(a0, 32, 64);
    a1 += __shfl_xor(a1, 32, 64);
    a2 += __shfl_xor(a2, 32, 64);
    a3 += __shfl_xor(a3, 32, 64);

    if (sub == 0) {
        float inv = 1.0f / z;
        float4 o = make_float4(a0 * inv, a1 * inv, a2 * inv, a3 * inv);
        *(float4*)&out[(size_t)wid * 128 + col] = o;
    }
}

extern "C" void kernel_launch(void* const* d_in, const int* in_sizes, int n_in,
                              void* d_out, int out_size, void* d_ws, size_t ws_size,
                              hipStream_t stream) {
    const float* hin = (const float*)d_in[0];
    const int*   src = (const int*)d_in[1];
    const int*   dst = (const int*)d_in[2];
    const float* Wq  = (const float*)d_in[3];
    const float* Wk  = (const float*)d_in[4];
    const float* Wv  = (const float*)d_in[5];
    const float* bq  = (const float*)d_in[6];
    const float* bk  = (const float*)d_in[7];
    const float* bv  = (const float*)d_in[8];

    const int N = in_sizes[0] / 128;
    const int E = in_sizes[1];
    const int NB = (N + 255) / 256;   // 196 for N=50000; scan_top assumes NB<=256

    float* out = (float*)d_out;

    // workspace layout (all chunks >=16B aligned)
    float* Q      = (float*)d_ws;                       // N*128 fp32
    short* KV     = (short*)(Q + (size_t)N * 128);      // N*256 bf16 (group-interleaved K|V)
    short* wswz   = KV + (size_t)N * 256;               // 49152 bf16
    int*   deg    = (int*)(wswz + 49152);               // N
    int*   cursor = deg + N;                            // N
    int*   esrc   = cursor + N;                         // E
    int*   row_start = esrc + E;                        // N+1
    int*   bsum   = row_start + N + 1;                  // NB
    int*   boff   = bsum + 256;                         // NB

    hipMemsetAsync(deg, 0, (size_t)N * sizeof(int), stream);

    gat_prep_50766513439004<<<(E + 255) / 256, 256, 0, stream>>>(
        Wq, Wk, Wv, dst, deg, wswz, E);

    gat_proj_50766513439004<<<(N + 63) / 64, 256, 0, stream>>>(
        hin, wswz, bq, bk, bv, Q, KV, N);

    gat_scan_blocks_50766513439004<<<NB, 256, 0, stream>>>(deg, bsum, N);
    gat_scan_top_50766513439004<<<1, 256, 0, stream>>>(bsum, boff, NB);
    gat_scan_down_50766513439004<<<NB, 256, 0, stream>>>(deg, boff, row_start, cursor, N);

    gat_scatter_50766513439004<<<(E + 255) / 256, 256, 0, stream>>>(
        src, dst, cursor, esrc, E);

    int gather_blocks = (N * 64 + 255) / 256;
    gat_gather_50766513439004<<<gather_blocks, 256, 0, stream>>>(
        Q, KV, row_start, esrc, out, N);
}